// Round 1
// baseline (2268.722 us; speedup 1.0000x reference)
//
#include <hip/hip_runtime.h>

#define HDIM 96
#define QDIM 24   // float4 quads per row

__global__ void deg_init_k(int* __restrict__ deg, int n) {
  int i = blockIdx.x * blockDim.x + threadIdx.x;
  if (i < n) deg[i] = 1;  // self-loop
}

__global__ void deg_count_k(const int* __restrict__ dst, int* __restrict__ deg, int e) {
  int i = blockIdx.x * blockDim.x + threadIdx.x;
  if (i < e) atomicAdd(&deg[dst[i]], 1);
}

__global__ void dis_k(const int* __restrict__ deg, float* __restrict__ dis, int n) {
  int i = blockIdx.x * blockDim.x + threadIdx.x;
  if (i < n) dis[i] = rsqrtf((float)deg[i]);
}

// agg[i,:] = dis[i]^2 * h[i,:]   (the self-loop message, also zero-inits agg)
__global__ void agg_init_k(const float* __restrict__ h, const float* __restrict__ dis,
                           float* __restrict__ agg, int n) {
  int t = blockIdx.x * blockDim.x + threadIdx.x;  // [0, n*QDIM)
  if (t >= n * QDIM) return;
  int i = t / QDIM;
  float w = dis[i]; w *= w;
  float4 v = ((const float4*)h)[t];
  v.x *= w; v.y *= w; v.z *= w; v.w *= w;
  ((float4*)agg)[t] = v;
}

// agg[dst,:] += dis[src]*dis[dst] * h[src,:]   one thread per (edge, float4-quad)
__global__ void scatter_k(const int* __restrict__ src, const int* __restrict__ dst,
                          const float* __restrict__ dis, const float* __restrict__ h,
                          float* __restrict__ agg, int e) {
  int t = blockIdx.x * blockDim.x + threadIdx.x;  // [0, e*QDIM) = 19.2M < 2^31
  if (t >= e * QDIM) return;
  int ei = t / QDIM;
  int q  = t - ei * QDIM;
  int s = src[ei], d = dst[ei];
  float w = dis[s] * dis[d];
  float4 v = ((const float4*)(h + (size_t)s * HDIM))[q];
  float* o = agg + (size_t)d * HDIM + 4 * q;
  unsafeAtomicAdd(o + 0, v.x * w);   // HW global_atomic_add_f32 (coarse-grained mem)
  unsafeAtomicAdd(o + 1, v.y * w);
  unsafeAtomicAdd(o + 2, v.z * w);
  unsafeAtomicAdd(o + 3, v.w * w);
}

// out[n,96] = A[n,96] @ W[96,96] (+bias) (+accum) (+relu)
// block = 192 threads: cg = t%24 -> 4 cols, rg = t/24 -> 8 rows; tile = 64 rows.
template<bool RELU, bool ACCUM, bool BIAS>
__global__ __launch_bounds__(192) void gemm96_k(
    const float* __restrict__ A, const float* __restrict__ W,
    const float* __restrict__ bias, float* __restrict__ out, int n) {
  __shared__ float Ws[HDIM * HDIM];   // 36864 B
  __shared__ float xs[64 * HDIM];     // 24576 B
  const int t = threadIdx.x;
  for (int i = t; i < HDIM * HDIM; i += 192) Ws[i] = W[i];
  const int row0 = blockIdx.x * 64;
  const int nrows = min(64, n - row0);
  for (int i = t; i < nrows * HDIM; i += 192) xs[i] = A[(size_t)row0 * HDIM + i];
  __syncthreads();

  const int cg = t % 24;        // column quad
  const int rg = t / 24;        // 0..7
  const int c0 = cg * 4;
  float acc[8][4];
#pragma unroll
  for (int j = 0; j < 8; j++) { acc[j][0]=0.f; acc[j][1]=0.f; acc[j][2]=0.f; acc[j][3]=0.f; }

  for (int k = 0; k < HDIM; k++) {
    const float4 w4 = *((const float4*)(Ws + k * HDIM + c0));
#pragma unroll
    for (int j = 0; j < 8; j++) {
      float xv = xs[(rg * 8 + j) * HDIM + k];
      acc[j][0] = fmaf(xv, w4.x, acc[j][0]);
      acc[j][1] = fmaf(xv, w4.y, acc[j][1]);
      acc[j][2] = fmaf(xv, w4.z, acc[j][2]);
      acc[j][3] = fmaf(xv, w4.w, acc[j][3]);
    }
  }

  float4 bv = make_float4(0.f, 0.f, 0.f, 0.f);
  if (BIAS) bv = *((const float4*)(bias + c0));
#pragma unroll
  for (int j = 0; j < 8; j++) {
    int r = rg * 8 + j;
    if (r < nrows) {
      float4 o;
      o.x = acc[j][0] + bv.x;
      o.y = acc[j][1] + bv.y;
      o.z = acc[j][2] + bv.z;
      o.w = acc[j][3] + bv.w;
      float4* op = (float4*)(out + (size_t)(row0 + r) * HDIM + c0);
      if (ACCUM) {
        float4 p = *op;
        o.x += p.x; o.y += p.y; o.z += p.z; o.w += p.w;
      }
      if (RELU) {
        o.x = fmaxf(o.x, 0.f); o.y = fmaxf(o.y, 0.f);
        o.z = fmaxf(o.z, 0.f); o.w = fmaxf(o.w, 0.f);
      }
      *op = o;
    }
  }
}

extern "C" void kernel_launch(void* const* d_in, const int* in_sizes, int n_in,
                              void* d_out, int out_size, void* d_ws, size_t ws_size,
                              hipStream_t stream) {
  const float* x       = (const float*)d_in[0];
  const int*   edge    = (const int*)d_in[1];   // [2, E]
  const float* W_local = (const float*)d_in[2];
  const float* b_local = (const float*)d_in[3];
  const float* W_g1    = (const float*)d_in[4];
  const float* b_g1    = (const float*)d_in[5];
  const float* W_g2    = (const float*)d_in[6];
  const float* b_g2    = (const float*)d_in[7];
  const float* W_fuse  = (const float*)d_in[8]; // [192, 96] row-major
  const float* b_fuse  = (const float*)d_in[9];
  float* out = (float*)d_out;

  const int n = in_sizes[0] / HDIM;
  const int e = in_sizes[1] / 2;
  const int* src = edge;
  const int* dst = edge + e;

  // workspace layout (all 256B-aligned): deg | dis | bufA | bufB | bufC
  char* ws = (char*)d_ws;
  int*   deg  = (int*)ws;    ws += ((size_t)n * 4 + 255) & ~(size_t)255;
  float* dis  = (float*)ws;  ws += ((size_t)n * 4 + 255) & ~(size_t)255;
  float* bufA = (float*)ws;  ws += (size_t)n * HDIM * 4;   // ax / ag2
  float* bufB = (float*)ws;  ws += (size_t)n * HDIM * 4;   // local
  float* bufC = (float*)ws;                                 // g1 / g2

  // degree + norm
  deg_init_k<<<(n + 255) / 256, 256, 0, stream>>>(deg, n);
  deg_count_k<<<(e + 255) / 256, 256, 0, stream>>>(dst, deg, e);
  dis_k<<<(n + 255) / 256, 256, 0, stream>>>(deg, dis, n);

  // ax = agg(x)  (aggregation commutes with the linear layers)
  agg_init_k<<<(n * QDIM + 255) / 256, 256, 0, stream>>>(x, dis, bufA, n);
  scatter_k<<<(e * QDIM + 255) / 256, 256, 0, stream>>>(src, dst, dis, x, bufA, e);

  const int gb = (n + 63) / 64;
  // local = relu(ax@W_local+b) ; g1 = relu(ax@W_g1+b)
  gemm96_k<true, false, true><<<gb, 192, 0, stream>>>(bufA, W_local, b_local, bufB, n);
  gemm96_k<true, false, true><<<gb, 192, 0, stream>>>(bufA, W_g1, b_g1, bufC, n);

  // ag2 = agg(g1) ; g2 = relu(ag2@W_g2+b)
  agg_init_k<<<(n * QDIM + 255) / 256, 256, 0, stream>>>(bufC, dis, bufA, n);
  scatter_k<<<(e * QDIM + 255) / 256, 256, 0, stream>>>(src, dst, dis, bufC, bufA, e);
  gemm96_k<true, false, true><<<gb, 192, 0, stream>>>(bufA, W_g2, b_g2, bufC, n);

  // out = local@Wf_top + g2@Wf_bot + b_fuse
  gemm96_k<false, false, true><<<gb, 192, 0, stream>>>(bufB, W_fuse, b_fuse, out, n);
  gemm96_k<false, true, false><<<gb, 192, 0, stream>>>(bufC, W_fuse + HDIM * HDIM, nullptr, out, n);
}

// Round 2
// 444.231 us; speedup vs baseline: 5.1071x; 5.1071x over previous
//
#include <hip/hip_runtime.h>

#define HDIM 96
#define QDIM 24   // float4 quads per row

__global__ void zero_k(int* __restrict__ p, int n) {
  int i = blockIdx.x * blockDim.x + threadIdx.x;
  if (i < n) p[i] = 0;
}

__global__ void deg_count_k(const int* __restrict__ dst, int* __restrict__ indeg, int e) {
  int i = blockIdx.x * blockDim.x + threadIdx.x;
  if (i < e) atomicAdd(&indeg[dst[i]], 1);
}

__global__ void dis_k(const int* __restrict__ indeg, float* __restrict__ dis, int n) {
  int i = blockIdx.x * blockDim.x + threadIdx.x;
  if (i < n) dis[i] = rsqrtf((float)(1 + indeg[i]));   // +1 self-loop
}

// Single-block exclusive scan of indeg[0..n) -> offsets[0..n], cursor copy.
// 1024 threads; per-chunk wave shfl scan + 16-wave-sum scan in LDS.
__global__ __launch_bounds__(1024) void scan_k(const int* __restrict__ indeg,
                                               int* __restrict__ offsets,
                                               int* __restrict__ cursor, int n) {
  __shared__ int wsum[16];
  __shared__ int carry_s;
  const int tid = threadIdx.x;
  const int lane = tid & 63, w = tid >> 6;
  if (tid == 0) carry_s = 0;
  __syncthreads();
  for (int base = 0; base < n; base += 1024) {
    const int i = base + tid;
    const int v = (i < n) ? indeg[i] : 0;
    // wave-level inclusive scan
    int incl = v;
#pragma unroll
    for (int off = 1; off < 64; off <<= 1) {
      int t = __shfl_up(incl, off, 64);
      if (lane >= off) incl += t;
    }
    if (lane == 63) wsum[w] = incl;
    __syncthreads();
    if (tid < 16) {
      int s = wsum[tid];
#pragma unroll
      for (int off = 1; off < 16; off <<= 1) {
        int t = __shfl_up(s, off, 16);
        if (tid >= off) s += t;
      }
      wsum[tid] = s;   // inclusive wave-sum scan
    }
    __syncthreads();
    const int carry = carry_s;
    incl += (w > 0 ? wsum[w - 1] : 0);
    if (i < n) {
      const int excl = carry + incl - v;
      offsets[i] = excl;
      cursor[i]  = excl;
    }
    __syncthreads();                     // all reads of carry_s / wsum done
    if (tid == 1023) carry_s = carry + incl;
    __syncthreads();
  }
  if (tid == 0) offsets[n] = carry_s;
}

__global__ void place_k(const int* __restrict__ src, const int* __restrict__ dst,
                        int* __restrict__ cursor, int* __restrict__ csr_src, int e) {
  int i = blockIdx.x * blockDim.x + threadIdx.x;
  if (i >= e) return;
  int d = dst[i];
  int slot = atomicAdd(&cursor[d], 1);
  csr_src[slot] = src[i];
}

// agg[d,:] = dis[d] * ( dis[d]*h[d,:] + sum_{s->d} dis[s]*h[s,:] )
// 24 lanes per node, one float4 quad each. block = 192 -> 8 nodes/block.
__global__ __launch_bounds__(192) void gather_k(
    const int* __restrict__ csr_src, const int* __restrict__ offsets,
    const float* __restrict__ dis, const float* __restrict__ h,
    float* __restrict__ agg, int n) {
  const int tid  = threadIdx.x;
  const int node = blockIdx.x * 8 + tid / QDIM;
  const int q    = tid % QDIM;
  if (node >= n) return;
  const float dd = dis[node];
  float4 acc = ((const float4*)(h + (size_t)node * HDIM))[q];
  acc.x *= dd; acc.y *= dd; acc.z *= dd; acc.w *= dd;   // self-loop term (dis[d]*h[d])
  int i = offsets[node];
  const int end = offsets[node + 1];
  for (; i + 1 < end; i += 2) {
    const int s0 = csr_src[i], s1 = csr_src[i + 1];
    const float w0 = dis[s0], w1 = dis[s1];
    const float4 v0 = ((const float4*)(h + (size_t)s0 * HDIM))[q];
    const float4 v1 = ((const float4*)(h + (size_t)s1 * HDIM))[q];
    acc.x = fmaf(w0, v0.x, acc.x); acc.y = fmaf(w0, v0.y, acc.y);
    acc.z = fmaf(w0, v0.z, acc.z); acc.w = fmaf(w0, v0.w, acc.w);
    acc.x = fmaf(w1, v1.x, acc.x); acc.y = fmaf(w1, v1.y, acc.y);
    acc.z = fmaf(w1, v1.z, acc.z); acc.w = fmaf(w1, v1.w, acc.w);
  }
  if (i < end) {
    const int s0 = csr_src[i];
    const float w0 = dis[s0];
    const float4 v0 = ((const float4*)(h + (size_t)s0 * HDIM))[q];
    acc.x = fmaf(w0, v0.x, acc.x); acc.y = fmaf(w0, v0.y, acc.y);
    acc.z = fmaf(w0, v0.z, acc.z); acc.w = fmaf(w0, v0.w, acc.w);
  }
  acc.x *= dd; acc.y *= dd; acc.z *= dd; acc.w *= dd;
  ((float4*)(agg + (size_t)node * HDIM))[q] = acc;
}

// out[n,96] = A[n,96] @ W[96,96] (+bias) (+accum) (+relu)
template<bool RELU, bool ACCUM, bool BIAS>
__global__ __launch_bounds__(192) void gemm96_k(
    const float* __restrict__ A, const float* __restrict__ W,
    const float* __restrict__ bias, float* __restrict__ out, int n) {
  __shared__ float Ws[HDIM * HDIM];
  __shared__ float xs[64 * HDIM];
  const int t = threadIdx.x;
  for (int i = t; i < HDIM * HDIM; i += 192) Ws[i] = W[i];
  const int row0 = blockIdx.x * 64;
  const int nrows = min(64, n - row0);
  for (int i = t; i < nrows * HDIM; i += 192) xs[i] = A[(size_t)row0 * HDIM + i];
  __syncthreads();

  const int cg = t % QDIM;
  const int rg = t / QDIM;
  const int c0 = cg * 4;
  float acc[8][4];
#pragma unroll
  for (int j = 0; j < 8; j++) { acc[j][0]=0.f; acc[j][1]=0.f; acc[j][2]=0.f; acc[j][3]=0.f; }

  for (int k = 0; k < HDIM; k++) {
    const float4 w4 = *((const float4*)(Ws + k * HDIM + c0));
#pragma unroll
    for (int j = 0; j < 8; j++) {
      float xv = xs[(rg * 8 + j) * HDIM + k];
      acc[j][0] = fmaf(xv, w4.x, acc[j][0]);
      acc[j][1] = fmaf(xv, w4.y, acc[j][1]);
      acc[j][2] = fmaf(xv, w4.z, acc[j][2]);
      acc[j][3] = fmaf(xv, w4.w, acc[j][3]);
    }
  }

  float4 bv = make_float4(0.f, 0.f, 0.f, 0.f);
  if (BIAS) bv = *((const float4*)(bias + c0));
#pragma unroll
  for (int j = 0; j < 8; j++) {
    int r = rg * 8 + j;
    if (r < nrows) {
      float4 o;
      o.x = acc[j][0] + bv.x;
      o.y = acc[j][1] + bv.y;
      o.z = acc[j][2] + bv.z;
      o.w = acc[j][3] + bv.w;
      float4* op = (float4*)(out + (size_t)(row0 + r) * HDIM + c0);
      if (ACCUM) {
        float4 p = *op;
        o.x += p.x; o.y += p.y; o.z += p.z; o.w += p.w;
      }
      if (RELU) {
        o.x = fmaxf(o.x, 0.f); o.y = fmaxf(o.y, 0.f);
        o.z = fmaxf(o.z, 0.f); o.w = fmaxf(o.w, 0.f);
      }
      *op = o;
    }
  }
}

extern "C" void kernel_launch(void* const* d_in, const int* in_sizes, int n_in,
                              void* d_out, int out_size, void* d_ws, size_t ws_size,
                              hipStream_t stream) {
  const float* x       = (const float*)d_in[0];
  const int*   edge    = (const int*)d_in[1];   // [2, E]
  const float* W_local = (const float*)d_in[2];
  const float* b_local = (const float*)d_in[3];
  const float* W_g1    = (const float*)d_in[4];
  const float* b_g1    = (const float*)d_in[5];
  const float* W_g2    = (const float*)d_in[6];
  const float* b_g2    = (const float*)d_in[7];
  const float* W_fuse  = (const float*)d_in[8]; // [192, 96] row-major
  const float* b_fuse  = (const float*)d_in[9];
  float* out = (float*)d_out;

  const int n = in_sizes[0] / HDIM;
  const int e = in_sizes[1] / 2;
  const int* src = edge;
  const int* dst = edge + e;

  // workspace layout (256B-aligned chunks)
  char* ws = (char*)d_ws;
  auto alloc = [&](size_t bytes) { char* p = ws; ws += (bytes + 255) & ~(size_t)255; return p; };
  int*   indeg   = (int*)alloc((size_t)n * 4);
  float* dis     = (float*)alloc((size_t)n * 4);
  int*   offsets = (int*)alloc((size_t)(n + 1) * 4);
  int*   cursor  = (int*)alloc((size_t)n * 4);
  int*   csr_src = (int*)alloc((size_t)e * 4);
  float* bufA    = (float*)alloc((size_t)n * HDIM * 4);   // ax / ag2
  float* bufB    = (float*)alloc((size_t)n * HDIM * 4);   // local
  float* bufC    = (float*)alloc((size_t)n * HDIM * 4);   // g1 / g2

  // degree + norm + CSR build
  zero_k<<<(n + 255) / 256, 256, 0, stream>>>(indeg, n);
  deg_count_k<<<(e + 255) / 256, 256, 0, stream>>>(dst, indeg, e);
  dis_k<<<(n + 255) / 256, 256, 0, stream>>>(indeg, dis, n);
  scan_k<<<1, 1024, 0, stream>>>(indeg, offsets, cursor, n);
  place_k<<<(e + 255) / 256, 256, 0, stream>>>(src, dst, cursor, csr_src, e);

  const int ggrid = (n + 7) / 8;
  const int gb = (n + 63) / 64;

  // ax = agg(x)  (aggregation commutes with the linear layers)
  gather_k<<<ggrid, 192, 0, stream>>>(csr_src, offsets, dis, x, bufA, n);

  // local = relu(ax@W_local+b) ; g1 = relu(ax@W_g1+b)
  gemm96_k<true, false, true><<<gb, 192, 0, stream>>>(bufA, W_local, b_local, bufB, n);
  gemm96_k<true, false, true><<<gb, 192, 0, stream>>>(bufA, W_g1, b_g1, bufC, n);

  // ag2 = agg(g1) ; g2 = relu(ag2@W_g2+b)
  gather_k<<<ggrid, 192, 0, stream>>>(csr_src, offsets, dis, bufC, bufA, n);
  gemm96_k<true, false, true><<<gb, 192, 0, stream>>>(bufA, W_g2, b_g2, bufC, n);

  // out = local@Wf_top + g2@Wf_bot + b_fuse
  gemm96_k<false, false, true><<<gb, 192, 0, stream>>>(bufB, W_fuse, b_fuse, out, n);
  gemm96_k<false, true, false><<<gb, 192, 0, stream>>>(bufC, W_fuse + HDIM * HDIM, nullptr, out, n);
}